// Round 4
// baseline (718.432 us; speedup 1.0000x reference)
//
#include <hip/hip_runtime.h>
#include <math.h>

#define B_   16
#define L_   8192
#define D_   64
#define R_   4
#define NB_  128   // n_buckets = L/64
#define NH_  64    // rand_matrix last dim = n_buckets/2

typedef float v2f __attribute__((ext_vector_type(2)));

// DPP helpers: quad-local (4-lane) broadcast / butterfly — pure VALU, no LDS pipe.
__device__ __forceinline__ float dpp_xor1(float x) {
    return __int_as_float(__builtin_amdgcn_mov_dpp(__float_as_int(x), 0xB1, 0xf, 0xf, true)); // quad_perm(1,0,3,2)
}
__device__ __forceinline__ float dpp_xor2(float x) {
    return __int_as_float(__builtin_amdgcn_mov_dpp(__float_as_int(x), 0x4E, 0xf, 0xf, true)); // quad_perm(2,3,0,1)
}
__device__ __forceinline__ float quad_bcast0(float x) {
    return __int_as_float(__builtin_amdgcn_mov_dpp(__float_as_int(x), 0x00, 0xf, 0xf, true));
}
__device__ __forceinline__ float quad_bcast1(float x) {
    return __int_as_float(__builtin_amdgcn_mov_dpp(__float_as_int(x), 0x55, 0xf, 0xf, true));
}
__device__ __forceinline__ float quad_bcast2(float x) {
    return __int_as_float(__builtin_amdgcn_mov_dpp(__float_as_int(x), 0xAA, 0xf, 0xf, true));
}
__device__ __forceinline__ float quad_bcast3(float x) {
    return __int_as_float(__builtin_amdgcn_mov_dpp(__float_as_int(x), 0xFF, 0xf, 0xf, true));
}

// Explicit wait macros for the async global->LDS K pipeline (k_flash).
#define VMCNT4 asm volatile("s_waitcnt vmcnt(4)" ::: "memory")
#define VMCNT0 asm volatile("s_waitcnt vmcnt(0)" ::: "memory")

// direct global->LDS 16B per lane; LDS dest is wave-uniform base + lane*16 (linear).
__device__ __forceinline__ void gl_lds16(const float* g, float* l) {
    __builtin_amdgcn_global_load_lds((const __attribute__((address_space(1))) void*)g,
                                     (__attribute__((address_space(3))) void*)l, 16, 0, 0);
}

// global sorted position of lookback key jj (0..127: prev chunk 0..63, cur 64..127)
__device__ __forceinline__ int kpos(int c, int jj) {
    return ((c + NB_ - 1 + (jj >> 6)) & (NB_ - 1)) * 64 + (jj & 63);
}

// ---------------- K1: normalize rand_matrix columns over d (fp64), store [b][r][n][d]
__global__ __launch_bounds__(64) void k_rmnorm(const float* __restrict__ rm, double* __restrict__ rmn) {
    int b = blockIdx.x >> 2, r = blockIdx.x & 3;
    int n = threadIdx.x;
    float v[D_];
    double ss = 0.0;
    #pragma unroll
    for (int d = 0; d < D_; ++d) {
        float f = rm[((size_t)(b * D_ + d) * R_ + r) * NH_ + n];
        v[d] = f;
        ss += (double)f * (double)f;
    }
    double nrm = sqrt(ss); if (nrm < 1e-12) nrm = 1e-12;
    double inv = 1.0 / nrm;
    double* o = rmn + ((size_t)(b * R_ + r) * NH_ + n) * D_;
    #pragma unroll
    for (int d = 0; d < D_; ++d) o[d] = (double)v[d] * inv;
}

// ---------------- K2: LSH hash — packed-fp32 argmax with top-2 margin test, fp64 re-check
// for near-tie lanes. fp32 dot error bound ~1.4e-6*||q||; margin 1.2e-5*||q|| = 8x safety.
__global__ __launch_bounds__(256) void k_hash(const float* __restrict__ q, const double* __restrict__ rmn,
                                              float* __restrict__ rn, int* __restrict__ h) {
    __shared__ float rms[NH_ * D_]; // 16 KB
    int b = blockIdx.z, r = blockIdx.y;
    int l = blockIdx.x * 256 + threadIdx.x;
    const double* src = rmn + (size_t)(b * R_ + r) * NH_ * D_;
    for (int i = threadIdx.x; i < NH_ * D_; i += 256) rms[i] = (float)src[i];
    const float* qp = q + ((size_t)b * L_ + l) * D_;
    v2f qv2[D_ / 2];
    double ss = 0.0;
    #pragma unroll
    for (int d = 0; d < D_; d += 4) {
        float4 f = *(const float4*)(qp + d);
        qv2[d >> 1]       = (v2f){f.x, f.y};
        qv2[(d >> 1) + 1] = (v2f){f.z, f.w};
        ss += (double)f.x * f.x + (double)f.y * f.y + (double)f.z * f.z + (double)f.w * f.w;
    }
    __syncthreads();
    float best = -1.0e30f, second = -1.0e30f; int bi = 0;
    for (int n = 0; n < NH_; ++n) {
        const float* kp = &rms[n * D_];
        v2f a0 = (v2f){0.f, 0.f}, a1 = a0;
        #pragma unroll
        for (int d = 0; d < D_; d += 4) {
            float4 kk = *(const float4*)(kp + d);
            a0 = __builtin_elementwise_fma(qv2[d >> 1],       (v2f){kk.x, kk.y}, a0);
            a1 = __builtin_elementwise_fma(qv2[(d >> 1) + 1], (v2f){kk.z, kk.w}, a1);
        }
        float s = (a0.x + a0.y) + (a1.x + a1.y);
        if (s > best)       { second = best; best = s; bi = n; }
        else if (s > second)  second = s;
        float ns = -s;
        if (ns > best)      { second = best; best = ns; bi = n + NH_; }
        else if (ns > second) second = ns;
    }
    float qn = (float)sqrt(ss);
    if (best - second < 1.2e-5f * qn + 1.0e-7f) {
        // near-tie: redo exactly as the proven fp64 path (same values, same order);
        // rmn read from global — lane-uniform addresses, broadcast, L2-resident.
        double bestd = -1.0e300; bi = 0;
        for (int n = 0; n < NH_; ++n) {
            const double* kp = src + n * D_;
            double a0 = 0, a1 = 0, a2 = 0, a3 = 0;
            #pragma unroll
            for (int d = 0; d < D_; d += 4) {
                a0 = fma((double)qv2[d >> 1].x,       kp[d],     a0);
                a1 = fma((double)qv2[d >> 1].y,       kp[d + 1], a1);
                a2 = fma((double)qv2[(d >> 1) + 1].x, kp[d + 2], a2);
                a3 = fma((double)qv2[(d >> 1) + 1].y, kp[d + 3], a3);
            }
            double s = (a0 + a1) + (a2 + a3);
            if (s > bestd)  { bestd = s;  bi = n; }
            if (-s > bestd) { bestd = -s; bi = n + NH_; }
        }
    }
    h[(size_t)(b * R_ + r) * L_ + l] = bi;
    if (r == 0) {
        double nrm = sqrt(ss); if (nrm < 1e-12) nrm = 1e-12;
        rn[(size_t)b * L_ + l] = (float)(1.0 / nrm);
    }
}

// ---------------- K3: stable counting sort by bucket per (b,r).
// 256 threads/block; counter matrix [bucket][thread] stride-257 padded.
// Emits packed per-position records rec[pos] = {l | bucket<<16, rn[l] raw bits}
// (8 B) consumed by k_flash via the SCALAR pipe.
__global__ __launch_bounds__(256) void k_sort(const int* __restrict__ h, const float* __restrict__ rn,
                                              int* __restrict__ iv, int2* __restrict__ rec) {
    __shared__ unsigned int cnt[NB_ * 257];  // 128.5 KB (fits 160 KB LDS)
    __shared__ unsigned int wsum[4];
    int br = blockIdx.x;
    const int* hh = h + (size_t)br * L_;
    const float* rnb = rn + (size_t)(br >> 2) * L_;
    int t = threadIdx.x;
    for (int i = t; i < NB_ * 257; i += 256) cnt[i] = 0;
    __syncthreads();
    int base = t * 32;                      // each thread owns 32 consecutive l
    for (int i = 0; i < 32; ++i) { int bk = hh[base + i]; cnt[bk * 257 + t]++; }
    __syncthreads();
    // exclusive scan over the flattened (bucket-major, thread-minor) 32768 cells.
    int fb = t * 128;                        // this thread's contiguous logical range
    unsigned int local = 0;
    for (int i = 0; i < 128; ++i) { unsigned g = fb + i; local += cnt[g + (g >> 8)]; }
    unsigned int v = local;
    #pragma unroll
    for (int off = 1; off < 64; off <<= 1) {
        unsigned int u = __shfl_up(v, off);
        if ((t & 63) >= off) v += u;
    }
    if ((t & 63) == 63) wsum[t >> 6] = v;
    __syncthreads();
    unsigned int wbase = 0;
    for (int w = 0; w < (t >> 6); ++w) wbase += wsum[w];
    unsigned int run = wbase + v - local;    // exclusive base for this thread's cells
    for (int i = 0; i < 128; ++i) {
        unsigned g = fb + i;
        unsigned int c0 = cnt[g + (g >> 8)];
        cnt[g + (g >> 8)] = run; run += c0;
    }
    __syncthreads();
    int* ivp = iv + (size_t)br * L_;
    int2* rp = rec + (size_t)br * L_;
    for (int i = 0; i < 32; ++i) {
        int l = base + i; int bk = hh[l];
        unsigned int pos = cnt[bk * 257 + t]++;
        ivp[l] = (int)pos;
        rp[pos] = make_int2(l | (bk << 16), __float_as_int(rnb[l]));
    }
}

// ---------------- K4: fused flash pass — QK^T, static-max softmax, PV in one sweep.
// R14: K in double-buffered LDS (async gl_lds, 4 ds_read_b128/j) + V in ROTATING
// REGISTERS software-pipelined ONE KEY AHEAD (4 global_load_dwordx4 for key j+1
// issued before key j's compute — a full ~400cy iteration of latency cover), with
// key records prefetched TWO ahead (kvC) so the scalar-load latency feeding the V
// address is also hidden. Rationale: R0/R1 (~60% VALUBusy, 0 conflicts) were
// LDS-pipe-throughput-bound at 8-9 ds_read_b128/j; R13's unprefetched global V
// (434us, 45% VALUBusy) exposed the V fetch latency serially per j. This version
// cuts LDS to 4 b128/j AND keeps V latency hidden.
// vmcnt discipline: stage-top vmcnt(4) retires the OLDEST in-flight loads — the
// staging of the buffer about to be read is always oldest, so the wait is correct
// under any interleaved compiler waits; prologue uses a one-time vmcnt(0) (issue
// order there is not protected by intervening compiler waits).
// Inner 16-j loop is compiler-unrolled: ps[j&3] static (no scratch), summation
// order bit-identical to the R11/R13 passing path. Staging and record fetch share
// kpos() — no index mismatch possible.
// omode: 0 = store O/sum + lse, contrib indexed [(b*R+r)*L + pos] (tierA)
//        1 = same but contrib indexed [b*L + pos] (tierB per-round slice)
//        2 = lse only (tierC pass 1)
//        3 = atomic w-weighted add into out (tierC pass 2; needs gm/gs)
__global__ __launch_bounds__(64, 2) void k_flash(const float* __restrict__ q, const float* __restrict__ val,
                                                 const int2* __restrict__ rec, float* __restrict__ lse,
                                                 const float* __restrict__ gm, const float* __restrict__ gs,
                                                 float* __restrict__ out, float* __restrict__ contrib,
                                                 int r_fixed, int omode) {
    __shared__ __align__(16) float kt[2][16 * 64];   // double-buffered 16-row K tiles (8 KB)
    int tid = threadIdx.x;
    int c = blockIdx.x, b = blockIdx.z;
    int r = (r_fixed < 0) ? (int)blockIdx.y : r_fixed;
    size_t sbase = (size_t)(b * R_ + r) * L_;
    const int2* recs = rec + sbase;
    const float* qb = q   + (size_t)b * L_ * D_;
    const float* vb = val + (size_t)b * L_ * D_;
    int loadv = (omode != 2);
    int h = tid & 3;
    int posq = c * 64 + (tid >> 2) * 4;           // first query of this lane's quad
    // own-query record (kl | bk<<16, rn) and the quad's 4 query rows
    int2 rown = recs[posq + h];
    int own_w0 = rown.x;
    int own_bk = own_w0 & 0xFFFF0000;
    float m_own = 0.125f / __int_as_float(rown.y);     // == ||q_own||/8 (R11 path)
    int mls[4];
    #pragma unroll
    for (int qq = 0; qq < 4; ++qq) mls[qq] = recs[posq + qq].x & 0xFFFF;
    int ownpos = posq + h;
    v2f qv2[4][8];
    #pragma unroll
    for (int qq = 0; qq < 4; ++qq) {
        const float* qp = qb + (size_t)mls[qq] * D_ + h * 16;
        #pragma unroll
        for (int i = 0; i < 16; i += 4) {
            float4 f = *(const float4*)(qp + i);
            qv2[qq][i >> 1]       = (v2f){f.x, f.y};
            qv2[qq][(i >> 1) + 1] = (v2f){f.z, f.w};
        }
    }
    float ps[4] = {0.0f, 0.0f, 0.0f, 0.0f};
    v2f acc2[4][8];
    #pragma unroll
    for (int qq = 0; qq < 4; ++qq)
        #pragma unroll
        for (int i = 0; i < 8; ++i) acc2[qq][i] = (v2f){0.0f, 0.0f};

    // prologue: stage 0 (keys 0..15) into buffer 0; prime the kv/V pipelines
    {
        int p0 = kpos(c, 0);
        #pragma unroll
        for (int t4 = 0; t4 < 4; ++t4) {
            int kl = recs[p0 + t4 * 4 + (tid >> 4)].x & 0xFFFF;
            gl_lds16(qb + (size_t)kl * D_ + ((tid & 15) * 4), &kt[0][t4 * 256]);
        }
    }
    int2 kvA = recs[kpos(c, 0)];
    int2 kvB = recs[kpos(c, 1)];
    float4 vA0, vA1, vA2, vA3, vB0, vB1, vB2, vB3;
    if (loadv) {
        const float* vp = vb + (size_t)(kvA.x & 0xFFFF) * D_ + h * 16;
        vA0 = ((const float4*)vp)[0]; vA1 = ((const float4*)vp)[1];
        vA2 = ((const float4*)vp)[2]; vA3 = ((const float4*)vp)[3];
    }

    #pragma unroll 1
    for (int s = 0; s < 8; ++s) {   // 8 stages of 16 keys: prev chunk (4) then current (4)
        // before reading kt[s&1]: its staging (oldest in-flight) must be retired.
        if (s == 0 || !loadv) { VMCNT0; } else { VMCNT4; }
        if (s < 7) {
            int bposn = kpos(c, (s + 1) * 16);
            float* dst = &kt[(s + 1) & 1][0];
            #pragma unroll
            for (int t4 = 0; t4 < 4; ++t4) {
                int kl = recs[bposn + t4 * 4 + (tid >> 4)].x & 0xFFFF;
                gl_lds16(qb + (size_t)kl * D_ + ((tid & 15) * 4), dst + t4 * 256);
            }
        }
        const float* ktp = &kt[s & 1][0];
        for (int j = 0; j < 16; ++j) {
            int jj = s * 16 + j;
            // prefetch key record two ahead (covers scalar-load latency for V addr)
            int jn = (jj < 126) ? jj + 2 : 127;
            int2 kvC = recs[kpos(c, jn)];
            // issue V row for key jj+1 (from kvB) — consumed next iteration
            if (loadv && jj < 127) {
                const float* vp = vb + (size_t)(kvB.x & 0xFFFF) * D_ + h * 16;
                vB0 = ((const float4*)vp)[0]; vB1 = ((const float4*)vp)[1];
                vB2 = ((const float4*)vp)[2]; vB3 = ((const float4*)vp)[3];
            }
            const float* kpj = ktp + j * 64 + h * 16;
            v2f a0 = (v2f){0.f, 0.f}, a1 = a0, a2 = a0, a3 = a0;
            #pragma unroll
            for (int i = 0; i < 16; i += 4) {
                float4 kk = *(const float4*)(kpj + i);
                v2f kA = (v2f){kk.x, kk.y}, kB = (v2f){kk.z, kk.w};
                int i2 = i >> 1;
                a0 = __builtin_elementwise_fma(qv2[0][i2], kA, a0);
                a0 = __builtin_elementwise_fma(qv2[0][i2 + 1], kB, a0);
                a1 = __builtin_elementwise_fma(qv2[1][i2], kA, a1);
                a1 = __builtin_elementwise_fma(qv2[1][i2 + 1], kB, a1);
                a2 = __builtin_elementwise_fma(qv2[2][i2], kA, a2);
                a2 = __builtin_elementwise_fma(qv2[2][i2 + 1], kB, a2);
                a3 = __builtin_elementwise_fma(qv2[3][i2], kA, a3);
                a3 = __builtin_elementwise_fma(qv2[3][i2 + 1], kB, a3);
            }
            float p0 = a0.x + a0.y, p1 = a1.x + a1.y, p2 = a2.x + a2.y, p3 = a3.x + a3.y;
            // 4x4 transpose-reduce across the quad: lane h ends with query h's full dot
            bool b0 = (h & 1), b1 = (h & 2) != 0;
            float u0 = b0 ? p1 : p0;
            float t0 = b0 ? p0 : p1;
            u0 += dpp_xor1(t0);
            float u2 = b0 ? p3 : p2;
            float t2 = b0 ? p2 : p3;
            u2 += dpp_xor1(t2);
            float dot = b1 ? u2 : u0;
            float t3 = b1 ? u0 : u2;
            dot += dpp_xor2(t3);
            float skr = __int_as_float(kvA.y) * 0.125f;       // rn_k * 0.125 (R11 path)
            float sc = dot * skr;
            sc = (own_bk == (kvA.x & 0xFFFF0000)) ? sc : -1.0e9f;  // cross-bucket mask
            if (own_w0 == kvA.x) sc = -1.0e5f;         // self mask (overrides, as in ref)
            float p = __expf(sc - m_own);              // static max: no rescaling ever
            ps[j & 3] += p;
            if (loadv) {
                v2f P0 = (v2f){quad_bcast0(p), quad_bcast0(p)};
                v2f P1 = (v2f){quad_bcast1(p), quad_bcast1(p)};
                v2f P2 = (v2f){quad_bcast2(p), quad_bcast2(p)};
                v2f P3 = (v2f){quad_bcast3(p), quad_bcast3(p)};
                v2f vA = (v2f){vA0.x, vA0.y}, vBv = (v2f){vA0.z, vA0.w};
                v2f vC = (v2f){vA1.x, vA1.y}, vD = (v2f){vA1.z, vA1.w};
                v2f vE = (v2f){vA2.x, vA2.y}, vF = (v2f){vA2.z, vA2.w};
                v2f vG = (v2f){vA3.x, vA3.y}, vH = (v2f){vA3.z, vA3.w};
                acc2[0][0] = __builtin_elementwise_fma(P0, vA,  acc2[0][0]);
                acc2[0][1] = __builtin_elementwise_fma(P0, vBv, acc2[0][1]);
                acc2[0][2] = __builtin_elementwise_fma(P0, vC,  acc2[0][2]);
                acc2[0][3] = __builtin_elementwise_fma(P0, vD,  acc2[0][3]);
                acc2[0][4] = __builtin_elementwise_fma(P0, vE,  acc2[0][4]);
                acc2[0][5] = __builtin_elementwise_fma(P0, vF,  acc2[0][5]);
                acc2[0][6] = __builtin_elementwise_fma(P0, vG,  acc2[0][6]);
                acc2[0][7] = __builtin_elementwise_fma(P0, vH,  acc2[0][7]);
                acc2[1][0] = __builtin_elementwise_fma(P1, vA,  acc2[1][0]);
                acc2[1][1] = __builtin_elementwise_fma(P1, vBv, acc2[1][1]);
                acc2[1][2] = __builtin_elementwise_fma(P1, vC,  acc2[1][2]);
                acc2[1][3] = __builtin_elementwise_fma(P1, vD,  acc2[1][3]);
                acc2[1][4] = __builtin_elementwise_fma(P1, vE,  acc2[1][4]);
                acc2[1][5] = __builtin_elementwise_fma(P1, vF,  acc2[1][5]);
                acc2[1][6] = __builtin_elementwise_fma(P1, vG,  acc2[1][6]);
                acc2[1][7] = __builtin_elementwise_fma(P1, vH,  acc2[1][7]);
                acc2[2][0] = __builtin_elementwise_fma(P2, vA,  acc2[2][0]);
                acc2[2][1] = __builtin_elementwise_fma(P2, vBv, acc2[2][1]);
                acc2[2][2] = __builtin_elementwise_fma(P2, vC,  acc2[2][2]);
                acc2[2][3] = __builtin_elementwise_fma(P2, vD,  acc2[2][3]);
                acc2[2][4] = __builtin_elementwise_fma(P2, vE,  acc2[2][4]);
                acc2[2][5] = __builtin_elementwise_fma(P2, vF,  acc2[2][5]);
                acc2[2][6] = __builtin_elementwise_fma(P2, vG,  acc2[2][6]);
                acc2[2][7] = __builtin_elementwise_fma(P2, vH,  acc2[2][7]);
                acc2[3][0] = __builtin_elementwise_fma(P3, vA,  acc2[3][0]);
                acc2[3][1] = __builtin_elementwise_fma(P3, vBv, acc2[3][1]);
                acc2[3][2] = __builtin_elementwise_fma(P3, vC,  acc2[3][2]);
                acc2[3][3] = __builtin_elementwise_fma(P3, vD,  acc2[3][3]);
                acc2[3][4] = __builtin_elementwise_fma(P3, vE,  acc2[3][4]);
                acc2[3][5] = __builtin_elementwise_fma(P3, vF,  acc2[3][5]);
                acc2[3][6] = __builtin_elementwise_fma(P3, vG,  acc2[3][6]);
                acc2[3][7] = __builtin_elementwise_fma(P3, vH,  acc2[3][7]);
            }
            // rotate the key/V pipelines
            kvA = kvB; kvB = kvC;
            if (loadv && jj < 127) { vA0 = vB0; vA1 = vB1; vA2 = vB2; vA3 = vB3; }
        }
    }
    float sum = (ps[0] + ps[1]) + (ps[2] + ps[3]);
    float lse_own, inv_own;
    if (sum > 0.0f) { lse_own = m_own + logf(sum); inv_own = 1.0f / sum; }
    else            { lse_own = -3.0e38f;          inv_own = 0.0f; }   // fully-masked row
    if (omode != 3) lse[sbase + ownpos] = lse_own;
    if (omode == 0 || omode == 1) {
        float ivs[4];
        ivs[0] = quad_bcast0(inv_own); ivs[1] = quad_bcast1(inv_own);
        ivs[2] = quad_bcast2(inv_own); ivs[3] = quad_bcast3(inv_own);
        float* cbase = contrib + ((omode == 0) ? (size_t)(b * R_ + r) * L_ : (size_t)b * L_) * D_;
        #pragma unroll
        for (int qq = 0; qq < 4; ++qq) {
            float* cp = cbase + (size_t)(posq + qq) * D_ + h * 16;
            #pragma unroll
            for (int i = 0; i < 16; i += 4) {
                int i2 = i >> 1;
                float4 o;
                o.x = acc2[qq][i2].x * ivs[qq];     o.y = acc2[qq][i2].y * ivs[qq];
                o.z = acc2[qq][i2 + 1].x * ivs[qq]; o.w = acc2[qq][i2 + 1].y * ivs[qq];
                *(float4*)(cp + i) = o;
            }
        }
    } else if (omode == 3) {
        int brr = b * R_ + r;
        float gmv = gm[brr], gsv = gs[brr];
        float ls4[4], iv4[4];
        ls4[0] = quad_bcast0(lse_own); ls4[1] = quad_bcast1(lse_own);
        ls4[2] = quad_bcast2(lse_own); ls4[3] = quad_bcast3(lse_own);
        iv4[0] = quad_bcast0(inv_own); iv4[1] = quad_bcast1(inv_own);
        iv4[2] = quad_bcast2(inv_own); iv4[3] = quad_bcast3(inv_own);
        #pragma unroll
        for (int qq = 0; qq < 4; ++qq) {
            float wq = __expf(ls4[qq] - gmv) * gsv * iv4[qq];
            float* op = out + ((size_t)b * L_ + mls[qq]) * D_ + h * 16;
            #pragma unroll
            for (int i = 0; i < 8; ++i) {
                unsafeAtomicAdd(op + 2 * i,     wq * acc2[qq][i].x);
                unsafeAtomicAdd(op + 2 * i + 1, wq * acc2[qq][i].y);
            }
        }
    }
}

// ---------------- K5: softmax-over-L normalizers (max + fp64 sum) per (b,r)
__global__ __launch_bounds__(256) void k_wred(const float* __restrict__ lse, float* __restrict__ gm,
                                              float* __restrict__ gs, int r_w) {
    __shared__ float  sm[4];
    __shared__ double sd[4];
    int br = (r_w < 0) ? (int)blockIdx.x : ((int)blockIdx.x * R_ + r_w);
    const float* x = lse + (size_t)br * L_;
    int t = threadIdx.x;
    float mx = -3.0e38f;
    for (int i = t; i < L_; i += 256) mx = fmaxf(mx, x[i]);
    #pragma unroll
    for (int o = 32; o; o >>= 1) mx = fmaxf(mx, __shfl_down(mx, o));
    if ((t & 63) == 0) sm[t >> 6] = mx;
    __syncthreads();
    mx = fmaxf(fmaxf(sm[0], sm[1]), fmaxf(sm[2], sm[3]));
    double s = 0.0;
    for (int i = t; i < L_; i += 256) s += exp((double)x[i] - (double)mx);
    #pragma unroll
    for (int o = 32; o; o >>= 1) s += __shfl_down(s, o);
    if ((t & 63) == 0) sd[t >> 6] = s;
    __syncthreads();
    if (t == 0) { gm[br] = mx; gs[br] = (float)(1.0 / (sd[0] + sd[1] + sd[2] + sd[3])); }
}

// ---------------- K6a: gather all 4 rounds from full contrib, apply w, write out
__global__ __launch_bounds__(256) void k_comb_full(const float* __restrict__ contrib,
                                                   const int* __restrict__ iv,
                                                   const float* __restrict__ lse,
                                                   const float* __restrict__ gm,
                                                   const float* __restrict__ gs,
                                                   float* __restrict__ out) {
    int gid = blockIdx.x * 256 + threadIdx.x;
    int row = gid >> 2;              // b*L + l
    int ch  = (gid & 3) * 16;
    int b = row >> 13, l = row & (L_ - 1);
    float s[16];
    #pragma unroll
    for (int i = 0; i < 16; ++i) s[i] = 0.0f;
    #pragma unroll
    for (int r = 0; r < R_; ++r) {
        int brr = b * R_ + r;
        int pos = iv[(size_t)brr * L_ + l];
        float w = expf(lse[(size_t)brr * L_ + pos] - gm[brr]) * gs[brr];
        const float* cp = contrib + ((size_t)brr * L_ + pos) * D_ + ch;
        #pragma unroll
        for (int i = 0; i < 16; i += 4) {
            float4 f = *(const float4*)(cp + i);
            s[i]   = fmaf(w, f.x, s[i]);   s[i+1] = fmaf(w, f.y, s[i+1]);
            s[i+2] = fmaf(w, f.z, s[i+2]); s[i+3] = fmaf(w, f.w, s[i+3]);
        }
    }
    float* op = out + (size_t)row * D_ + ch;
    #pragma unroll
    for (int i = 0; i < 16; i += 4) {
        float4 o; o.x = s[i]; o.y = s[i+1]; o.z = s[i+2]; o.w = s[i+3];
        *(float4*)(op + i) = o;
    }
}

// ---------------- K6b: gather one round's slice, apply w, accumulate into out
__global__ __launch_bounds__(256) void k_comb_add(const float* __restrict__ contrib,
                                                  const int* __restrict__ iv,
                                                  const float* __restrict__ lse,
                                                  const float* __restrict__ gm,
                                                  const float* __restrict__ gs,
                                                  float* __restrict__ out, int r) {
    int gid = blockIdx.x * 256 + threadIdx.x;
    int row = gid >> 2;              // b*L + l
    int ch  = (gid & 3) * 16;
    int b = row >> 13, l = row & (L_ - 1);
    int brr = b * R_ + r;
    int pos = iv[(size_t)brr * L_ + l];
    float w = expf(lse[(size_t)brr * L_ + pos] - gm[brr]) * gs[brr];
    const float* cp = contrib + ((size_t)b * L_ + pos) * D_ + ch;
    float* op = out + (size_t)row * D_ + ch;
    #pragma unroll
    for (int i = 0; i < 16; i += 4) {
        float4 f = *(const float4*)(cp + i);
        float4 o = *(const float4*)(op + i);
        o.x = fmaf(w, f.x, o.x); o.y = fmaf(w, f.y, o.y);
        o.z = fmaf(w, f.z, o.z); o.w = fmaf(w, f.w, o.w);
        *(float4*)(op + i) = o;
    }
}

// ---------------- workspace layout (bytes)
// rec (int2, 4 MB) OVERLAYS rmn (fp64, 2 MB): rmn is dead after k_hash; rec is
// written by k_sort which runs after k_hash (stream-ordered).
#define OFF_RMN     0u           // double, 2 MB (k_rmnorm -> k_hash)
#define OFF_REC     0u           // int2,   4 MB (k_sort   -> k_flash), overlays RMN
#define OFF_RN      4194304u     // float,  512 KB
#define OFF_H       4718592u     // int,    2 MB
#define OFF_LSE     6815744u     // float,  2 MB
#define OFF_GM      8912896u
#define OFF_GS      8913152u
#define OFF_INV     8913408u     // int,    2 MB
#define OFF_CONTRIB 11010560u
#define CONTRIB_FULL_BYTES  134217728ull   // B*R*L*D*4 = 128 MiB
#define CONTRIB_SLICE_BYTES 33554432ull    // B*L*D*4   =  32 MiB

extern "C" void kernel_launch(void* const* d_in, const int* in_sizes, int n_in,
                              void* d_out, int out_size, void* d_ws, size_t ws_size,
                              hipStream_t stream) {
    const float* q  = (const float*)d_in[0];
    const float* v  = (const float*)d_in[1];
    const float* rm = (const float*)d_in[2];
    float* out = (float*)d_out;
    char* ws = (char*)d_ws;
    double* rmn = (double*)(ws + OFF_RMN);
    int2*   rec = (int2*)(ws + OFF_REC);
    float*  rn  = (float*)(ws + OFF_RN);
    int*    h   = (int*)(ws + OFF_H);
    float*  lse = (float*)(ws + OFF_LSE);
    float*  gm  = (float*)(ws + OFF_GM);
    float*  gs  = (float*)(ws + OFF_GS);
    int*    iv  = (int*)(ws + OFF_INV);
    float*  contrib = (float*)(ws + OFF_CONTRIB);

    int tierA = (ws_size >= (size_t)OFF_CONTRIB + CONTRIB_FULL_BYTES) ? 1 : 0;
    int tierB = (!tierA && ws_size >= (size_t)OFF_CONTRIB + CONTRIB_SLICE_BYTES) ? 1 : 0;

    hipLaunchKernelGGL(k_rmnorm, dim3(B_ * R_), dim3(64), 0, stream, rm, rmn);
    hipLaunchKernelGGL(k_hash, dim3(L_ / 256, R_, B_), dim3(256), 0, stream, q, rmn, rn, h);
    hipLaunchKernelGGL(k_sort, dim3(B_ * R_), dim3(256), 0, stream, h, rn, iv, rec);

    if (tierA) {
        hipLaunchKernelGGL(k_flash, dim3(NB_, R_, B_), dim3(64), 0, stream, q, v, rec,
                           lse, gm, gs, out, contrib, -1, 0);
        hipLaunchKernelGGL(k_wred, dim3(B_ * R_), dim3(256), 0, stream, lse, gm, gs, -1);
        hipLaunchKernelGGL(k_comb_full, dim3(B_ * L_ * 4 / 256), dim3(256), 0, stream,
                           contrib, iv, lse, gm, gs, out);
    } else if (tierB) {
        hipMemsetAsync(d_out, 0, (size_t)B_ * L_ * D_ * sizeof(float), stream);
        for (int r = 0; r < R_; ++r) {
            hipLaunchKernelGGL(k_flash, dim3(NB_, 1, B_), dim3(64), 0, stream, q, v, rec,
                               lse, gm, gs, out, contrib, r, 1);
            hipLaunchKernelGGL(k_wred, dim3(B_), dim3(256), 0, stream, lse, gm, gs, r);
            hipLaunchKernelGGL(k_comb_add, dim3(B_ * L_ * 4 / 256), dim3(256), 0, stream,
                               contrib, iv, lse, gm, gs, out, r);
        }
    } else {
        // tier C: two flash passes (lse-only, then atomic w-weighted accumulate)
        hipMemsetAsync(d_out, 0, (size_t)B_ * L_ * D_ * sizeof(float), stream);
        hipLaunchKernelGGL(k_flash, dim3(NB_, R_, B_), dim3(64), 0, stream, q, v, rec,
                           lse, gm, gs, out, contrib, -1, 2);
        hipLaunchKernelGGL(k_wred, dim3(B_ * R_), dim3(256), 0, stream, lse, gm, gs, -1);
        hipLaunchKernelGGL(k_flash, dim3(NB_, R_, B_), dim3(64), 0, stream, q, v, rec,
                           lse, gm, gs, out, contrib, -1, 3);
    }
}

// Round 5
// 572.859 us; speedup vs baseline: 1.2541x; 1.2541x over previous
//
#include <hip/hip_runtime.h>
#include <math.h>

#define B_   16
#define L_   8192
#define D_   64
#define R_   4
#define NB_  128   // n_buckets = L/64
#define NH_  64    // rand_matrix last dim = n_buckets/2

typedef float v2f __attribute__((ext_vector_type(2)));

// DPP helpers: quad-local (4-lane) broadcast / butterfly — pure VALU, no LDS pipe.
__device__ __forceinline__ float dpp_xor1(float x) {
    return __int_as_float(__builtin_amdgcn_mov_dpp(__float_as_int(x), 0xB1, 0xf, 0xf, true)); // quad_perm(1,0,3,2)
}
__device__ __forceinline__ float dpp_xor2(float x) {
    return __int_as_float(__builtin_amdgcn_mov_dpp(__float_as_int(x), 0x4E, 0xf, 0xf, true)); // quad_perm(2,3,0,1)
}
__device__ __forceinline__ float quad_bcast0(float x) {
    return __int_as_float(__builtin_amdgcn_mov_dpp(__float_as_int(x), 0x00, 0xf, 0xf, true));
}
__device__ __forceinline__ float quad_bcast1(float x) {
    return __int_as_float(__builtin_amdgcn_mov_dpp(__float_as_int(x), 0x55, 0xf, 0xf, true));
}
__device__ __forceinline__ float quad_bcast2(float x) {
    return __int_as_float(__builtin_amdgcn_mov_dpp(__float_as_int(x), 0xAA, 0xf, 0xf, true));
}
__device__ __forceinline__ float quad_bcast3(float x) {
    return __int_as_float(__builtin_amdgcn_mov_dpp(__float_as_int(x), 0xFF, 0xf, 0xf, true));
}

// ---------------- K1: normalize rand_matrix columns over d (fp64), store [b][r][n][d]
__global__ __launch_bounds__(64) void k_rmnorm(const float* __restrict__ rm, double* __restrict__ rmn) {
    int b = blockIdx.x >> 2, r = blockIdx.x & 3;
    int n = threadIdx.x;
    float v[D_];
    double ss = 0.0;
    #pragma unroll
    for (int d = 0; d < D_; ++d) {
        float f = rm[((size_t)(b * D_ + d) * R_ + r) * NH_ + n];
        v[d] = f;
        ss += (double)f * (double)f;
    }
    double nrm = sqrt(ss); if (nrm < 1e-12) nrm = 1e-12;
    double inv = 1.0 / nrm;
    double* o = rmn + ((size_t)(b * R_ + r) * NH_ + n) * D_;
    #pragma unroll
    for (int d = 0; d < D_; ++d) o[d] = (double)v[d] * inv;
}

// ---------------- K2: LSH hash — packed-fp32 argmax with top-2 margin test, fp64 re-check
// for near-tie lanes. fp32 dot error bound ~1.4e-6*||q||; margin 1.2e-5*||q|| = 8x safety.
__global__ __launch_bounds__(256) void k_hash(const float* __restrict__ q, const double* __restrict__ rmn,
                                              float* __restrict__ rn, int* __restrict__ h) {
    __shared__ float rms[NH_ * D_]; // 16 KB
    int b = blockIdx.z, r = blockIdx.y;
    int l = blockIdx.x * 256 + threadIdx.x;
    const double* src = rmn + (size_t)(b * R_ + r) * NH_ * D_;
    for (int i = threadIdx.x; i < NH_ * D_; i += 256) rms[i] = (float)src[i];
    const float* qp = q + ((size_t)b * L_ + l) * D_;
    v2f qv2[D_ / 2];
    double ss = 0.0;
    #pragma unroll
    for (int d = 0; d < D_; d += 4) {
        float4 f = *(const float4*)(qp + d);
        qv2[d >> 1]       = (v2f){f.x, f.y};
        qv2[(d >> 1) + 1] = (v2f){f.z, f.w};
        ss += (double)f.x * f.x + (double)f.y * f.y + (double)f.z * f.z + (double)f.w * f.w;
    }
    __syncthreads();
    float best = -1.0e30f, second = -1.0e30f; int bi = 0;
    for (int n = 0; n < NH_; ++n) {
        const float* kp = &rms[n * D_];
        v2f a0 = (v2f){0.f, 0.f}, a1 = a0;
        #pragma unroll
        for (int d = 0; d < D_; d += 4) {
            float4 kk = *(const float4*)(kp + d);
            a0 = __builtin_elementwise_fma(qv2[d >> 1],       (v2f){kk.x, kk.y}, a0);
            a1 = __builtin_elementwise_fma(qv2[(d >> 1) + 1], (v2f){kk.z, kk.w}, a1);
        }
        float s = (a0.x + a0.y) + (a1.x + a1.y);
        if (s > best)       { second = best; best = s; bi = n; }
        else if (s > second)  second = s;
        float ns = -s;
        if (ns > best)      { second = best; best = ns; bi = n + NH_; }
        else if (ns > second) second = ns;
    }
    float qn = (float)sqrt(ss);
    if (best - second < 1.2e-5f * qn + 1.0e-7f) {
        // near-tie: redo exactly as the proven fp64 path (same values, same order);
        // rmn read from global — lane-uniform addresses, broadcast, L2-resident.
        double bestd = -1.0e300; bi = 0;
        for (int n = 0; n < NH_; ++n) {
            const double* kp = src + n * D_;
            double a0 = 0, a1 = 0, a2 = 0, a3 = 0;
            #pragma unroll
            for (int d = 0; d < D_; d += 4) {
                a0 = fma((double)qv2[d >> 1].x,       kp[d],     a0);
                a1 = fma((double)qv2[d >> 1].y,       kp[d + 1], a1);
                a2 = fma((double)qv2[(d >> 1) + 1].x, kp[d + 2], a2);
                a3 = fma((double)qv2[(d >> 1) + 1].y, kp[d + 3], a3);
            }
            double s = (a0 + a1) + (a2 + a3);
            if (s > bestd)  { bestd = s;  bi = n; }
            if (-s > bestd) { bestd = -s; bi = n + NH_; }
        }
    }
    h[(size_t)(b * R_ + r) * L_ + l] = bi;
    if (r == 0) {
        double nrm = sqrt(ss); if (nrm < 1e-12) nrm = 1e-12;
        rn[(size_t)b * L_ + l] = (float)(1.0 / nrm);
    }
}

// ---------------- K3: stable counting sort by bucket per (b,r).
// 256 threads/block; counter matrix [bucket][thread] stride-257 padded.
// Emits packed per-position records rec[pos] = {l | bucket<<16, rn[l] raw bits}.
__global__ __launch_bounds__(256) void k_sort(const int* __restrict__ h, const float* __restrict__ rn,
                                              int* __restrict__ iv, int2* __restrict__ rec) {
    __shared__ unsigned int cnt[NB_ * 257];  // 128.5 KB (fits 160 KB LDS)
    __shared__ unsigned int wsum[4];
    int br = blockIdx.x;
    const int* hh = h + (size_t)br * L_;
    const float* rnb = rn + (size_t)(br >> 2) * L_;
    int t = threadIdx.x;
    for (int i = t; i < NB_ * 257; i += 256) cnt[i] = 0;
    __syncthreads();
    int base = t * 32;                      // each thread owns 32 consecutive l
    for (int i = 0; i < 32; ++i) { int bk = hh[base + i]; cnt[bk * 257 + t]++; }
    __syncthreads();
    // exclusive scan over the flattened (bucket-major, thread-minor) 32768 cells.
    int fb = t * 128;                        // this thread's contiguous logical range
    unsigned int local = 0;
    for (int i = 0; i < 128; ++i) { unsigned g = fb + i; local += cnt[g + (g >> 8)]; }
    unsigned int v = local;
    #pragma unroll
    for (int off = 1; off < 64; off <<= 1) {
        unsigned int u = __shfl_up(v, off);
        if ((t & 63) >= off) v += u;
    }
    if ((t & 63) == 63) wsum[t >> 6] = v;
    __syncthreads();
    unsigned int wbase = 0;
    for (int w = 0; w < (t >> 6); ++w) wbase += wsum[w];
    unsigned int run = wbase + v - local;    // exclusive base for this thread's cells
    for (int i = 0; i < 128; ++i) {
        unsigned g = fb + i;
        unsigned int c0 = cnt[g + (g >> 8)];
        cnt[g + (g >> 8)] = run; run += c0;
    }
    __syncthreads();
    int* ivp = iv + (size_t)br * L_;
    int2* rp = rec + (size_t)br * L_;
    for (int i = 0; i < 32; ++i) {
        int l = base + i; int bk = hh[l];
        unsigned int pos = cnt[bk * 257 + t]++;
        ivp[l] = (int)pos;
        rp[pos] = make_int2(l | (bk << 16), __float_as_int(rnb[l]));
    }
}

// ---------------- K4: fused flash pass — QK^T, static-max softmax, PV in one sweep.
// R15 = RECOVERY to the proven-best R0 structure (303us: V staged in LDS, 2-wave
// blocks, VGPR-roundtrip staging, no barriers — single-wave LDS write->read ordering
// via compiler lgkmcnt, validated R6) + three de-serializations:
//   (1) per-key scalars merged into ONE int4 krc table (1 ds_read_b128/j, was 3 b32);
//   (2) krc + V row software-pipelined ONE j AHEAD in registers (fully unrolled 16-j
//       loop, static indices) — the V reads and the record feeding the score move off
//       the ~160cy per-j dependency chain; K reads stay JIT from LDS (they head the
//       chain, covered by the previous j's tail);
//   (3) __launch_bounds__(128,2) so the pipeline regs don't spill.
// R13/R14 lesson: per-j global V (even prefetched) costs +130us — LDS broadcast reads
// of 4-distinct-address rows are far cheaper than a 64-lane VMEM gather. Keep V in LDS.
// rec decode (l|bk<<16, raw rn bits) proven in R13/R14; arithmetic bit-identical.
// omode: 0 = store O/sum + lse, contrib indexed [(b*R+r)*L + pos] (tierA)
//        1 = same but contrib indexed [b*L + pos] (tierB per-round slice)
//        2 = lse only (tierC pass 1)
//        3 = atomic w-weighted add into out (tierC pass 2; needs gm/gs)
__global__ __launch_bounds__(128, 2) void k_flash(const float* __restrict__ q, const float* __restrict__ val,
                                                  const int2* __restrict__ rec, float* __restrict__ lse,
                                                  const float* __restrict__ gm, const float* __restrict__ gs,
                                                  float* __restrict__ out, float* __restrict__ contrib,
                                                  int r_fixed, int omode) {
    __shared__ float kt[2][16 * 80];   // per-wave: 16 rows x 4 slices @ stride 20 words
    __shared__ float vt[2][16 * 80];
    __shared__ int4  krc[2][16];       // {l|bk<<16, rn bits, 0, 0} per key
    int w   = threadIdx.x >> 6;
    int tid = threadIdx.x & 63;
    int c = blockIdx.x * 2 + w, b = blockIdx.z;
    int r = (r_fixed < 0) ? (int)blockIdx.y : r_fixed;
    size_t sbase = (size_t)(b * R_ + r) * L_;
    const int2* recs = rec + sbase;
    const float* qb = q   + (size_t)b * L_ * D_;
    const float* vb = val + (size_t)b * L_ * D_;
    int loadv = (omode != 2);
    int h = tid & 3;
    int posq = c * 64 + (tid >> 2) * 4;           // first query of this lane's quad
    int2 rown = recs[posq + h];
    int own_w0 = rown.x;
    int own_bk = own_w0 & 0xFFFF0000;
    float m_own = 0.125f / __int_as_float(rown.y);   // == ||q_own||/8
    int mls[4];
    #pragma unroll
    for (int qq = 0; qq < 4; ++qq) mls[qq] = recs[posq + qq].x & 0xFFFF;
    int ownpos = posq + h;
    v2f qv2[4][8];
    #pragma unroll
    for (int qq = 0; qq < 4; ++qq) {
        const float* qp = qb + (size_t)mls[qq] * D_ + h * 16;
        #pragma unroll
        for (int i = 0; i < 16; i += 4) {
            float4 f = *(const float4*)(qp + i);
            qv2[qq][i >> 1]       = (v2f){f.x, f.y};
            qv2[qq][(i >> 1) + 1] = (v2f){f.z, f.w};
        }
    }
    float ps[4] = {0.0f, 0.0f, 0.0f, 0.0f};
    v2f acc2[4][8];
    #pragma unroll
    for (int qq = 0; qq < 4; ++qq)
        #pragma unroll
        for (int i = 0; i < 8; ++i) acc2[qq][i] = (v2f){0.0f, 0.0f};

    #pragma unroll 1
    for (int s = 0; s < 8; ++s) {   // 8 stages of 16 keys: prev chunk (4) then current (4)
        int ck = ((c + NB_ - 1 + (s >> 2)) & (NB_ - 1)) * 64 + (s & 3) * 16;
        {
            int rw = tid >> 2, cc = tid & 3;
            int kl = recs[ck + rw].x & 0xFFFF;
            const float* kp = qb + (size_t)kl * D_ + cc * 16;
            float* kd = &kt[w][rw * 80 + cc * 20];
            #pragma unroll
            for (int i = 0; i < 16; i += 4) *(float4*)(kd + i) = *(const float4*)(kp + i);
            if (loadv) {
                const float* vp = vb + (size_t)kl * D_ + cc * 16;
                float* vd = &vt[w][rw * 80 + cc * 20];
                #pragma unroll
                for (int i = 0; i < 16; i += 4) *(float4*)(vd + i) = *(const float4*)(vp + i);
            }
            if (tid < 16) {
                int2 rr = recs[ck + tid];
                krc[w][tid] = make_int4(rr.x, rr.y, 0, 0);
            }
        }
        // no barrier: single-wave producer/consumer, lgkmcnt ordering suffices (R6)
        // prime the 1-ahead pipeline for j=0
        int4 kvA = krc[w][0];
        float4 vA0, vA1, vA2, vA3;
        if (loadv) {
            const float* vp0 = &vt[w][0 * 80 + h * 20];
            vA0 = *(const float4*)(vp0 + 0);  vA1 = *(const float4*)(vp0 + 4);
            vA2 = *(const float4*)(vp0 + 8);  vA3 = *(const float4*)(vp0 + 12);
        }
        #pragma unroll
        for (int j = 0; j < 16; ++j) {
            int4 kvB;
            float4 vB0, vB1, vB2, vB3;
            if (j < 15) {
                kvB = krc[w][j + 1];
                if (loadv) {
                    const float* vpn = &vt[w][(j + 1) * 80 + h * 20];
                    vB0 = *(const float4*)(vpn + 0);  vB1 = *(const float4*)(vpn + 4);
                    vB2 = *(const float4*)(vpn + 8);  vB3 = *(const float4*)(vpn + 12);
                }
            }
            const float* kpj = &kt[w][j * 80 + h * 20];
            v2f a0 = (v2f){0.f, 0.f}, a1 = a0, a2 = a0, a3 = a0;
            #pragma unroll
            for (int i = 0; i < 16; i += 4) {
                float4 kk = *(const float4*)(kpj + i);
                v2f kA = (v2f){kk.x, kk.y}, kB = (v2f){kk.z, kk.w};
                int i2 = i >> 1;
                a0 = __builtin_elementwise_fma(qv2[0][i2], kA, a0);
                a0 = __builtin_elementwise_fma(qv2[0][i2 + 1], kB, a0);
                a1 = __builtin_elementwise_fma(qv2[1][i2], kA, a1);
                a1 = __builtin_elementwise_fma(qv2[1][i2 + 1], kB, a1);
                a2 = __builtin_elementwise_fma(qv2[2][i2], kA, a2);
                a2 = __builtin_elementwise_fma(qv2[2][i2 + 1], kB, a2);
                a3 = __builtin_elementwise_fma(qv2[3][i2], kA, a3);
                a3 = __builtin_elementwise_fma(qv2[3][i2 + 1], kB, a3);
            }
            float p0 = a0.x + a0.y, p1 = a1.x + a1.y, p2 = a2.x + a2.y, p3 = a3.x + a3.y;
            // 4x4 transpose-reduce across the quad: lane h ends with query h's full dot
            bool b0 = (h & 1), b1 = (h & 2) != 0;
            float u0 = b0 ? p1 : p0;
            float t0 = b0 ? p0 : p1;
            u0 += dpp_xor1(t0);
            float u2 = b0 ? p3 : p2;
            float t2 = b0 ? p2 : p3;
            u2 += dpp_xor1(t2);
            float dot = b1 ? u2 : u0;
            float t3 = b1 ? u0 : u2;
            dot += dpp_xor2(t3);
            float skr = __int_as_float(kvA.y) * 0.125f;       // rn_k * 0.125
            float sc = dot * skr;
            sc = (own_bk == (kvA.x & 0xFFFF0000)) ? sc : -1.0e9f;  // cross-bucket mask
            if (own_w0 == kvA.x) sc = -1.0e5f;         // self mask (overrides, as in ref)
            float p = __expf(sc - m_own);              // static max: no rescaling ever
            ps[j & 3] += p;
            if (loadv) {
                v2f P0 = (v2f){quad_bcast0(p), quad_bcast0(p)};
                v2f P1 = (v2f){quad_bcast1(p), quad_bcast1(p)};
                v2f P2 = (v2f){quad_bcast2(p), quad_bcast2(p)};
                v2f P3 = (v2f){quad_bcast3(p), quad_bcast3(p)};
                v2f vAa = (v2f){vA0.x, vA0.y}, vAb = (v2f){vA0.z, vA0.w};
                v2f vAc = (v2f){vA1.x, vA1.y}, vAd = (v2f){vA1.z, vA1.w};
                v2f vAe = (v2f){vA2.x, vA2.y}, vAf = (v2f){vA2.z, vA2.w};
                v2f vAg = (v2f){vA3.x, vA3.y}, vAh = (v2f){vA3.z, vA3.w};
                acc2[0][0] = __builtin_elementwise_fma(P0, vAa, acc2[0][0]);
                acc2[0][1] = __builtin_elementwise_fma(P0, vAb, acc2[0][1]);
                acc2[0][2] = __builtin_elementwise_fma(P0, vAc, acc2[0][2]);
                acc2[0][3] = __builtin_elementwise_fma(P0, vAd, acc2[0][3]);
                acc2[0][4] = __builtin_elementwise_fma(P0, vAe, acc2[0][4]);
                acc2[0][5] = __builtin_elementwise_fma(P0, vAf, acc2[0][5]);
                acc2[0][6] = __builtin_elementwise_fma(P0, vAg, acc2[0][6]);
                acc2[0][7] = __builtin_elementwise_fma(P0, vAh, acc2[0][7]);
                acc2[1][0] = __builtin_elementwise_fma(P1, vAa, acc2[1][0]);
                acc2[1][1] = __builtin_elementwise_fma(P1, vAb, acc2[1][1]);
                acc2[1][2] = __builtin_elementwise_fma(P1, vAc, acc2[1][2]);
                acc2[1][3] = __builtin_elementwise_fma(P1, vAd, acc2[1][3]);
                acc2[1][4] = __builtin_elementwise_fma(P1, vAe, acc2[1][4]);
                acc2[1][5] = __builtin_elementwise_fma(P1, vAf, acc2[1][5]);
                acc2[1][6] = __builtin_elementwise_fma(P1, vAg, acc2[1][6]);
                acc2[1][7] = __builtin_elementwise_fma(P1, vAh, acc2[1][7]);
                acc2[2][0] = __builtin_elementwise_fma(P2, vAa, acc2[2][0]);
                acc2[2][1] = __builtin_elementwise_fma(P2, vAb, acc2[2][1]);
                acc2[2][2] = __builtin_elementwise_fma(P2, vAc, acc2[2][2]);
                acc2[2][3] = __builtin_elementwise_fma(P2, vAd, acc2[2][3]);
                acc2[2][4] = __builtin_elementwise_fma(P2, vAe, acc2[2][4]);
                acc2[2][5] = __builtin_elementwise_fma(P2, vAf, acc2[2][5]);
                acc2[2][6] = __builtin_elementwise_fma(P2, vAg, acc2[2][6]);
                acc2[2][7] = __builtin_elementwise_fma(P2, vAh, acc2[2][7]);
                acc2[3][0] = __builtin_elementwise_fma(P3, vAa, acc2[3][0]);
                acc2[3][1] = __builtin_elementwise_fma(P3, vAb, acc2[3][1]);
                acc2[3][2] = __builtin_elementwise_fma(P3, vAc, acc2[3][2]);
                acc2[3][3] = __builtin_elementwise_fma(P3, vAd, acc2[3][3]);
                acc2[3][4] = __builtin_elementwise_fma(P3, vAe, acc2[3][4]);
                acc2[3][5] = __builtin_elementwise_fma(P3, vAf, acc2[3][5]);
                acc2[3][6] = __builtin_elementwise_fma(P3, vAg, acc2[3][6]);
                acc2[3][7] = __builtin_elementwise_fma(P3, vAh, acc2[3][7]);
            }
            if (j < 15) {
                kvA = kvB;
                if (loadv) { vA0 = vB0; vA1 = vB1; vA2 = vB2; vA3 = vB3; }
            }
        }
    }
    float sum = (ps[0] + ps[1]) + (ps[2] + ps[3]);
    float lse_own, inv_own;
    if (sum > 0.0f) { lse_own = m_own + logf(sum); inv_own = 1.0f / sum; }
    else            { lse_own = -3.0e38f;          inv_own = 0.0f; }   // fully-masked row
    if (omode != 3) lse[sbase + ownpos] = lse_own;
    if (omode == 0 || omode == 1) {
        float ivs[4];
        ivs[0] = quad_bcast0(inv_own); ivs[1] = quad_bcast1(inv_own);
        ivs[2] = quad_bcast2(inv_own); ivs[3] = quad_bcast3(inv_own);
        float* cbase = contrib + ((omode == 0) ? (size_t)(b * R_ + r) * L_ : (size_t)b * L_) * D_;
        #pragma unroll
        for (int qq = 0; qq < 4; ++qq) {
            float* cp = cbase + (size_t)(posq + qq) * D_ + h * 16;
            #pragma unroll
            for (int i = 0; i < 16; i += 4) {
                int i2 = i >> 1;
                float4 o;
                o.x = acc2[qq][i2].x * ivs[qq];     o.y = acc2[qq][i2].y * ivs[qq];
                o.z = acc2[qq][i2 + 1].x * ivs[qq]; o.w = acc2[qq][i2 + 1].y * ivs[qq];
                *(float4*)(cp + i) = o;
            }
        }
    } else if (omode == 3) {
        int brr = b * R_ + r;
        float gmv = gm[brr], gsv = gs[brr];
        float ls4[4], iv4[4];
        ls4[0] = quad_bcast0(lse_own); ls4[1] = quad_bcast1(lse_own);
        ls4[2] = quad_bcast2(lse_own); ls4[3] = quad_bcast3(lse_own);
        iv4[0] = quad_bcast0(inv_own); iv4[1] = quad_bcast1(inv_own);
        iv4[2] = quad_bcast2(inv_own); iv4[3] = quad_bcast3(inv_own);
        #pragma unroll
        for (int qq = 0; qq < 4; ++qq) {
            float wq = __expf(ls4[qq] - gmv) * gsv * iv4[qq];
            float* op = out + ((size_t)b * L_ + mls[qq]) * D_ + h * 16;
            #pragma unroll
            for (int i = 0; i < 8; ++i) {
                unsafeAtomicAdd(op + 2 * i,     wq * acc2[qq][i].x);
                unsafeAtomicAdd(op + 2 * i + 1, wq * acc2[qq][i].y);
            }
        }
    }
}

// ---------------- K5: softmax-over-L normalizers (max + fp64 sum) per (b,r)
__global__ __launch_bounds__(256) void k_wred(const float* __restrict__ lse, float* __restrict__ gm,
                                              float* __restrict__ gs, int r_w) {
    __shared__ float  sm[4];
    __shared__ double sd[4];
    int br = (r_w < 0) ? (int)blockIdx.x : ((int)blockIdx.x * R_ + r_w);
    const float* x = lse + (size_t)br * L_;
    int t = threadIdx.x;
    float mx = -3.0e38f;
    for (int i = t; i < L_; i += 256) mx = fmaxf(mx, x[i]);
    #pragma unroll
    for (int o = 32; o; o >>= 1) mx = fmaxf(mx, __shfl_down(mx, o));
    if ((t & 63) == 0) sm[t >> 6] = mx;
    __syncthreads();
    mx = fmaxf(fmaxf(sm[0], sm[1]), fmaxf(sm[2], sm[3]));
    double s = 0.0;
    for (int i = t; i < L_; i += 256) s += exp((double)x[i] - (double)mx);
    #pragma unroll
    for (int o = 32; o; o >>= 1) s += __shfl_down(s, o);
    if ((t & 63) == 0) sd[t >> 6] = s;
    __syncthreads();
    if (t == 0) { gm[br] = mx; gs[br] = (float)(1.0 / (sd[0] + sd[1] + sd[2] + sd[3])); }
}

// ---------------- K6a: gather all 4 rounds from full contrib, apply w, write out
__global__ __launch_bounds__(256) void k_comb_full(const float* __restrict__ contrib,
                                                   const int* __restrict__ iv,
                                                   const float* __restrict__ lse,
                                                   const float* __restrict__ gm,
                                                   const float* __restrict__ gs,
                                                   float* __restrict__ out) {
    int gid = blockIdx.x * 256 + threadIdx.x;
    int row = gid >> 2;              // b*L + l
    int ch  = (gid & 3) * 16;
    int b = row >> 13, l = row & (L_ - 1);
    float s[16];
    #pragma unroll
    for (int i = 0; i < 16; ++i) s[i] = 0.0f;
    #pragma unroll
    for (int r = 0; r < R_; ++r) {
        int brr = b * R_ + r;
        int pos = iv[(size_t)brr * L_ + l];
        float w = expf(lse[(size_t)brr * L_ + pos] - gm[brr]) * gs[brr];
        const float* cp = contrib + ((size_t)brr * L_ + pos) * D_ + ch;
        #pragma unroll
        for (int i = 0; i < 16; i += 4) {
            float4 f = *(const float4*)(cp + i);
            s[i]   = fmaf(w, f.x, s[i]);   s[i+1] = fmaf(w, f.y, s[i+1]);
            s[i+2] = fmaf(w, f.z, s[i+2]); s[i+3] = fmaf(w, f.w, s[i+3]);
        }
    }
    float* op = out + (size_t)row * D_ + ch;
    #pragma unroll
    for (int i = 0; i < 16; i += 4) {
        float4 o; o.x = s[i]; o.y = s[i+1]; o.z = s[i+2]; o.w = s[i+3];
        *(float4*)(op + i) = o;
    }
}

// ---------------- K6b: gather one round's slice, apply w, accumulate into out
__global__ __launch_bounds__(256) void k_comb_add(const float* __restrict__ contrib,
                                                  const int* __restrict__ iv,
                                                  const float* __restrict__ lse,
                                                  const float* __restrict__ gm,
                                                  const float* __restrict__ gs,
                                                  float* __restrict__ out, int r) {
    int gid = blockIdx.x * 256 + threadIdx.x;
    int row = gid >> 2;              // b*L + l
    int ch  = (gid & 3) * 16;
    int b = row >> 13, l = row & (L_ - 1);
    int brr = b * R_ + r;
    int pos = iv[(size_t)brr * L_ + l];
    float w = expf(lse[(size_t)brr * L_ + pos] - gm[brr]) * gs[brr];
    const float* cp = contrib + ((size_t)b * L_ + pos) * D_ + ch;
    float* op = out + (size_t)row * D_ + ch;
    #pragma unroll
    for (int i = 0; i < 16; i += 4) {
        float4 f = *(const float4*)(cp + i);
        float4 o = *(const float4*)(op + i);
        o.x = fmaf(w, f.x, o.x); o.y = fmaf(w, f.y, o.y);
        o.z = fmaf(w, f.z, o.z); o.w = fmaf(w, f.w, o.w);
        *(float4*)(op + i) = o;
    }
}

// ---------------- workspace layout (bytes)
// rec (int2, 4 MB) OVERLAYS rmn (fp64, 2 MB): rmn is dead after k_hash; rec is
// written by k_sort which runs after k_hash (stream-ordered).
#define OFF_RMN     0u           // double, 2 MB (k_rmnorm -> k_hash)
#define OFF_REC     0u           // int2,   4 MB (k_sort   -> k_flash), overlays RMN
#define OFF_RN      4194304u     // float,  512 KB
#define OFF_H       4718592u     // int,    2 MB
#define OFF_LSE     6815744u     // float,  2 MB
#define OFF_GM      8912896u
#define OFF_GS      8913152u
#define OFF_INV     8913408u     // int,    2 MB
#define OFF_CONTRIB 11010560u
#define CONTRIB_FULL_BYTES  134217728ull   // B*R*L*D*4 = 128 MiB
#define CONTRIB_SLICE_BYTES 33554432ull    // B*L*D*4   =  32 MiB

extern "C" void kernel_launch(void* const* d_in, const int* in_sizes, int n_in,
                              void* d_out, int out_size, void* d_ws, size_t ws_size,
                              hipStream_t stream) {
    const float* q  = (const float*)d_in[0];
    const float* v  = (const float*)d_in[1];
    const float* rm = (const float*)d_in[2];
    float* out = (float*)d_out;
    char* ws = (char*)d_ws;
    double* rmn = (double*)(ws + OFF_RMN);
    int2*   rec = (int2*)(ws + OFF_REC);
    float*  rn  = (float*)(ws + OFF_RN);
    int*    h   = (int*)(ws + OFF_H);
    float*  lse = (float*)(ws + OFF_LSE);
    float*  gm  = (float*)(ws + OFF_GM);
    float*  gs  = (float*)(ws + OFF_GS);
    int*    iv  = (int*)(ws + OFF_INV);
    float*  contrib = (float*)(ws + OFF_CONTRIB);

    int tierA = (ws_size >= (size_t)OFF_CONTRIB + CONTRIB_FULL_BYTES) ? 1 : 0;
    int tierB = (!tierA && ws_size >= (size_t)OFF_CONTRIB + CONTRIB_SLICE_BYTES) ? 1 : 0;

    hipLaunchKernelGGL(k_rmnorm, dim3(B_ * R_), dim3(64), 0, stream, rm, rmn);
    hipLaunchKernelGGL(k_hash, dim3(L_ / 256, R_, B_), dim3(256), 0, stream, q, rmn, rn, h);
    hipLaunchKernelGGL(k_sort, dim3(B_ * R_), dim3(256), 0, stream, h, rn, iv, rec);

    if (tierA) {
        hipLaunchKernelGGL(k_flash, dim3(NB_ / 2, R_, B_), dim3(128), 0, stream, q, v, rec,
                           lse, gm, gs, out, contrib, -1, 0);
        hipLaunchKernelGGL(k_wred, dim3(B_ * R_), dim3(256), 0, stream, lse, gm, gs, -1);
        hipLaunchKernelGGL(k_comb_full, dim3(B_ * L_ * 4 / 256), dim3(256), 0, stream,
                           contrib, iv, lse, gm, gs, out);
    } else if (tierB) {
        hipMemsetAsync(d_out, 0, (size_t)B_ * L_ * D_ * sizeof(float), stream);
        for (int r = 0; r < R_; ++r) {
            hipLaunchKernelGGL(k_flash, dim3(NB_ / 2, 1, B_), dim3(128), 0, stream, q, v, rec,
                               lse, gm, gs, out, contrib, r, 1);
            hipLaunchKernelGGL(k_wred, dim3(B_), dim3(256), 0, stream, lse, gm, gs, r);
            hipLaunchKernelGGL(k_comb_add, dim3(B_ * L_ * 4 / 256), dim3(256), 0, stream,
                               contrib, iv, lse, gm, gs, out, r);
        }
    } else {
        // tier C: two flash passes (lse-only, then atomic w-weighted accumulate)
        hipMemsetAsync(d_out, 0, (size_t)B_ * L_ * D_ * sizeof(float), stream);
        hipLaunchKernelGGL(k_flash, dim3(NB_ / 2, R_, B_), dim3(128), 0, stream, q, v, rec,
                           lse, gm, gs, out, contrib, -1, 2);
        hipLaunchKernelGGL(k_wred, dim3(B_ * R_), dim3(256), 0, stream, lse, gm, gs, -1);
        hipLaunchKernelGGL(k_flash, dim3(NB_ / 2, R_, B_), dim3(128), 0, stream, q, v, rec,
                           lse, gm, gs, out, contrib, -1, 3);
    }
}

// Round 6
// 530.053 us; speedup vs baseline: 1.3554x; 1.0808x over previous
//
#include <hip/hip_runtime.h>
#include <math.h>

#define B_   16
#define L_   8192
#define D_   64
#define R_   4
#define NB_  128   // n_buckets = L/64
#define NH_  64    // rand_matrix last dim = n_buckets/2

typedef float v2f __attribute__((ext_vector_type(2)));

// DPP helpers: quad-local (4-lane) broadcast / butterfly — pure VALU, no LDS pipe.
__device__ __forceinline__ float dpp_xor1(float x) {
    return __int_as_float(__builtin_amdgcn_mov_dpp(__float_as_int(x), 0xB1, 0xf, 0xf, true)); // quad_perm(1,0,3,2)
}
__device__ __forceinline__ float dpp_xor2(float x) {
    return __int_as_float(__builtin_amdgcn_mov_dpp(__float_as_int(x), 0x4E, 0xf, 0xf, true)); // quad_perm(2,3,0,1)
}
__device__ __forceinline__ float quad_bcast0(float x) {
    return __int_as_float(__builtin_amdgcn_mov_dpp(__float_as_int(x), 0x00, 0xf, 0xf, true));
}
__device__ __forceinline__ float quad_bcast1(float x) {
    return __int_as_float(__builtin_amdgcn_mov_dpp(__float_as_int(x), 0x55, 0xf, 0xf, true));
}
__device__ __forceinline__ float quad_bcast2(float x) {
    return __int_as_float(__builtin_amdgcn_mov_dpp(__float_as_int(x), 0xAA, 0xf, 0xf, true));
}
__device__ __forceinline__ float quad_bcast3(float x) {
    return __int_as_float(__builtin_amdgcn_mov_dpp(__float_as_int(x), 0xFF, 0xf, 0xf, true));
}

// ---------------- K1: normalize rand_matrix columns over d (fp64), store [b][r][n][d]
__global__ __launch_bounds__(64) void k_rmnorm(const float* __restrict__ rm, double* __restrict__ rmn) {
    int b = blockIdx.x >> 2, r = blockIdx.x & 3;
    int n = threadIdx.x;
    float v[D_];
    double ss = 0.0;
    #pragma unroll
    for (int d = 0; d < D_; ++d) {
        float f = rm[((size_t)(b * D_ + d) * R_ + r) * NH_ + n];
        v[d] = f;
        ss += (double)f * (double)f;
    }
    double nrm = sqrt(ss); if (nrm < 1e-12) nrm = 1e-12;
    double inv = 1.0 / nrm;
    double* o = rmn + ((size_t)(b * R_ + r) * NH_ + n) * D_;
    #pragma unroll
    for (int d = 0; d < D_; ++d) o[d] = (double)v[d] * inv;
}

// ---------------- K2: LSH hash — packed-fp32 argmax with top-2 margin test, fp64 re-check
// for near-tie lanes. fp32 dot error bound ~1.4e-6*||q||; margin 1.2e-5*||q|| = 8x safety.
__global__ __launch_bounds__(256) void k_hash(const float* __restrict__ q, const double* __restrict__ rmn,
                                              float* __restrict__ rn, int* __restrict__ h) {
    __shared__ float rms[NH_ * D_]; // 16 KB
    int b = blockIdx.z, r = blockIdx.y;
    int l = blockIdx.x * 256 + threadIdx.x;
    const double* src = rmn + (size_t)(b * R_ + r) * NH_ * D_;
    for (int i = threadIdx.x; i < NH_ * D_; i += 256) rms[i] = (float)src[i];
    const float* qp = q + ((size_t)b * L_ + l) * D_;
    v2f qv2[D_ / 2];
    double ss = 0.0;
    #pragma unroll
    for (int d = 0; d < D_; d += 4) {
        float4 f = *(const float4*)(qp + d);
        qv2[d >> 1]       = (v2f){f.x, f.y};
        qv2[(d >> 1) + 1] = (v2f){f.z, f.w};
        ss += (double)f.x * f.x + (double)f.y * f.y + (double)f.z * f.z + (double)f.w * f.w;
    }
    __syncthreads();
    float best = -1.0e30f, second = -1.0e30f; int bi = 0;
    for (int n = 0; n < NH_; ++n) {
        const float* kp = &rms[n * D_];
        v2f a0 = (v2f){0.f, 0.f}, a1 = a0;
        #pragma unroll
        for (int d = 0; d < D_; d += 4) {
            float4 kk = *(const float4*)(kp + d);
            a0 = __builtin_elementwise_fma(qv2[d >> 1],       (v2f){kk.x, kk.y}, a0);
            a1 = __builtin_elementwise_fma(qv2[(d >> 1) + 1], (v2f){kk.z, kk.w}, a1);
        }
        float s = (a0.x + a0.y) + (a1.x + a1.y);
        if (s > best)       { second = best; best = s; bi = n; }
        else if (s > second)  second = s;
        float ns = -s;
        if (ns > best)      { second = best; best = ns; bi = n + NH_; }
        else if (ns > second) second = ns;
    }
    float qn = (float)sqrt(ss);
    if (best - second < 1.2e-5f * qn + 1.0e-7f) {
        // near-tie: redo exactly as the proven fp64 path (same values, same order);
        // rmn read from global — lane-uniform addresses, broadcast, L2-resident.
        double bestd = -1.0e300; bi = 0;
        for (int n = 0; n < NH_; ++n) {
            const double* kp = src + n * D_;
            double a0 = 0, a1 = 0, a2 = 0, a3 = 0;
            #pragma unroll
            for (int d = 0; d < D_; d += 4) {
                a0 = fma((double)qv2[d >> 1].x,       kp[d],     a0);
                a1 = fma((double)qv2[d >> 1].y,       kp[d + 1], a1);
                a2 = fma((double)qv2[(d >> 1) + 1].x, kp[d + 2], a2);
                a3 = fma((double)qv2[(d >> 1) + 1].y, kp[d + 3], a3);
            }
            double s = (a0 + a1) + (a2 + a3);
            if (s > bestd)  { bestd = s;  bi = n; }
            if (-s > bestd) { bestd = -s; bi = n + NH_; }
        }
    }
    h[(size_t)(b * R_ + r) * L_ + l] = bi;
    if (r == 0) {
        double nrm = sqrt(ss); if (nrm < 1e-12) nrm = 1e-12;
        rn[(size_t)b * L_ + l] = (float)(1.0 / nrm);
    }
}

// ---------------- K3: stable counting sort by bucket per (b,r).
// 256 threads/block; counter matrix [bucket][thread] stride-257 padded.
// Emits packed per-position records rec[pos] = {l | bucket<<16, rn[l] raw bits}.
__global__ __launch_bounds__(256) void k_sort(const int* __restrict__ h, const float* __restrict__ rn,
                                              int* __restrict__ iv, int2* __restrict__ rec) {
    __shared__ unsigned int cnt[NB_ * 257];  // 128.5 KB (fits 160 KB LDS)
    __shared__ unsigned int wsum[4];
    int br = blockIdx.x;
    const int* hh = h + (size_t)br * L_;
    const float* rnb = rn + (size_t)(br >> 2) * L_;
    int t = threadIdx.x;
    for (int i = t; i < NB_ * 257; i += 256) cnt[i] = 0;
    __syncthreads();
    int base = t * 32;                      // each thread owns 32 consecutive l
    for (int i = 0; i < 32; ++i) { int bk = hh[base + i]; cnt[bk * 257 + t]++; }
    __syncthreads();
    // exclusive scan over the flattened (bucket-major, thread-minor) 32768 cells.
    int fb = t * 128;                        // this thread's contiguous logical range
    unsigned int local = 0;
    for (int i = 0; i < 128; ++i) { unsigned g = fb + i; local += cnt[g + (g >> 8)]; }
    unsigned int v = local;
    #pragma unroll
    for (int off = 1; off < 64; off <<= 1) {
        unsigned int u = __shfl_up(v, off);
        if ((t & 63) >= off) v += u;
    }
    if ((t & 63) == 63) wsum[t >> 6] = v;
    __syncthreads();
    unsigned int wbase = 0;
    for (int w = 0; w < (t >> 6); ++w) wbase += wsum[w];
    unsigned int run = wbase + v - local;    // exclusive base for this thread's cells
    for (int i = 0; i < 128; ++i) {
        unsigned g = fb + i;
        unsigned int c0 = cnt[g + (g >> 8)];
        cnt[g + (g >> 8)] = run; run += c0;
    }
    __syncthreads();
    int* ivp = iv + (size_t)br * L_;
    int2* rp = rec + (size_t)br * L_;
    for (int i = 0; i < 32; ++i) {
        int l = base + i; int bk = hh[l];
        unsigned int pos = cnt[bk * 257 + t]++;
        ivp[l] = (int)pos;
        rp[pos] = make_int2(l | (bk << 16), __float_as_int(rnb[l]));
    }
}

// ---------------- K4: fused flash pass — QK^T, static-max softmax, PV in one sweep.
// R16 = R0 champion structure (V staged in LDS, 2-wave blocks, JIT per-j reads, no
// barriers — single-wave LDS ordering via compiler lgkmcnt, validated R6) + BUCKET-
// RANGE SKIPPING (exact):
//   Keys are hash-sorted, so this wave's 64 queries span buckets [minbk,maxbk] =
//   buckets of its first/last position. Any key with bucket outside that range is
//   cross-bucket-masked for EVERY query: sc=-1e9 -> __expf==0.0f -> its entire
//   QK+reduce+exp+PV adds bit-exact zero. Dead keys are a sorted prefix of the
//   lookback window, so whole 16-key stages skip (staging included) via one scalar
//   range test; partial stages skip per-key via readfirstlane -> uniform branch.
//   Current-chunk stages are never dead (they contain the queries). Expected ~25%
//   of j-work and ~2/8 staging stages eliminated on average.
// R15 lesson: the 1-ahead register pipeline was pure overhead (-22us) — reverted to
// JIT reads. R13/R14 lesson: V stays in LDS. Per-key scalars in ONE int2 krc table
// (1 ds_read_b64/j, was 3 b32 in R0).
// omode: 0 = store O/sum + lse, contrib indexed [(b*R+r)*L + pos] (tierA)
//        1 = same but contrib indexed [b*L + pos] (tierB per-round slice)
//        2 = lse only (tierC pass 1)
//        3 = atomic w-weighted add into out (tierC pass 2; needs gm/gs)
__global__ __launch_bounds__(128, 2) void k_flash(const float* __restrict__ q, const float* __restrict__ val,
                                                  const int2* __restrict__ rec, float* __restrict__ lse,
                                                  const float* __restrict__ gm, const float* __restrict__ gs,
                                                  float* __restrict__ out, float* __restrict__ contrib,
                                                  int r_fixed, int omode) {
    __shared__ float kt[2][16 * 80];   // per-wave: 16 rows x 4 slices @ stride 20 words
    __shared__ float vt[2][16 * 80];
    __shared__ int2  krc[2][16];       // {l|bk<<16, rn bits} per key
    int w   = threadIdx.x >> 6;
    int tid = threadIdx.x & 63;
    int c = blockIdx.x * 2 + w, b = blockIdx.z;
    int r = (r_fixed < 0) ? (int)blockIdx.y : r_fixed;
    size_t sbase = (size_t)(b * R_ + r) * L_;
    const int2* recs = rec + sbase;
    const float* qb = q   + (size_t)b * L_ * D_;
    const float* vb = val + (size_t)b * L_ * D_;
    int loadv = (omode != 2);
    int h = tid & 3;
    int posq = c * 64 + (tid >> 2) * 4;           // first query of this lane's quad
    int2 rown = recs[posq + h];
    int own_w0 = rown.x;
    int own_bk = own_w0 & 0xFFFF0000;
    float m_own = 0.125f / __int_as_float(rown.y);   // == ||q_own||/8
    // wave query-bucket range (positions sorted by bucket -> first/last suffice)
    int minbk = __builtin_amdgcn_readfirstlane(recs[c * 64].x) & 0xFFFF0000;
    int maxbk = __builtin_amdgcn_readfirstlane(recs[c * 64 + 63].x) & 0xFFFF0000;
    int mls[4];
    #pragma unroll
    for (int qq = 0; qq < 4; ++qq) mls[qq] = recs[posq + qq].x & 0xFFFF;
    int ownpos = posq + h;
    v2f qv2[4][8];
    #pragma unroll
    for (int qq = 0; qq < 4; ++qq) {
        const float* qp = qb + (size_t)mls[qq] * D_ + h * 16;
        #pragma unroll
        for (int i = 0; i < 16; i += 4) {
            float4 f = *(const float4*)(qp + i);
            qv2[qq][i >> 1]       = (v2f){f.x, f.y};
            qv2[qq][(i >> 1) + 1] = (v2f){f.z, f.w};
        }
    }
    float ps[4] = {0.0f, 0.0f, 0.0f, 0.0f};
    v2f acc2[4][8];
    #pragma unroll
    for (int qq = 0; qq < 4; ++qq)
        #pragma unroll
        for (int i = 0; i < 8; ++i) acc2[qq][i] = (v2f){0.0f, 0.0f};

    #pragma unroll 1
    for (int s = 0; s < 8; ++s) {   // 8 stages of 16 keys: prev chunk (4) then current (4)
        int ck = ((c + NB_ - 1 + (s >> 2)) & (NB_ - 1)) * 64 + (s & 3) * 16;
        // stage-level skip: keys sorted within stage -> range test vs query buckets.
        // Dead stage contributes exactly 0 to ps/acc (expf(-1e9-m)==0.0f) -> exact.
        int sfir = __builtin_amdgcn_readfirstlane(recs[ck].x) & 0xFFFF0000;
        int slas = __builtin_amdgcn_readfirstlane(recs[ck + 15].x) & 0xFFFF0000;
        if (slas < minbk || sfir > maxbk) continue;
        {
            int rw = tid >> 2, cc = tid & 3;
            int kl = recs[ck + rw].x & 0xFFFF;
            const float* kp = qb + (size_t)kl * D_ + cc * 16;
            float* kd = &kt[w][rw * 80 + cc * 20];
            #pragma unroll
            for (int i = 0; i < 16; i += 4) *(float4*)(kd + i) = *(const float4*)(kp + i);
            if (loadv) {
                const float* vp = vb + (size_t)kl * D_ + cc * 16;
                float* vd = &vt[w][rw * 80 + cc * 20];
                #pragma unroll
                for (int i = 0; i < 16; i += 4) *(float4*)(vd + i) = *(const float4*)(vp + i);
            }
            if (tid < 16) krc[w][tid] = recs[ck + tid];
        }
        // no barrier: single-wave producer/consumer, lgkmcnt ordering suffices (R6)
        #pragma unroll
        for (int j = 0; j < 16; ++j) {
            int2 kv = krc[w][j];
            // per-key skip (uniform branch): bucket outside wave range -> exact zero
            int bkj = __builtin_amdgcn_readfirstlane(kv.x) & 0xFFFF0000;
            if (bkj < minbk || bkj > maxbk) continue;
            const float* kpj = &kt[w][j * 80 + h * 20];
            v2f a0 = (v2f){0.f, 0.f}, a1 = a0, a2 = a0, a3 = a0;
            #pragma unroll
            for (int i = 0; i < 16; i += 4) {
                float4 kk = *(const float4*)(kpj + i);
                v2f kA = (v2f){kk.x, kk.y}, kB = (v2f){kk.z, kk.w};
                int i2 = i >> 1;
                a0 = __builtin_elementwise_fma(qv2[0][i2], kA, a0);
                a0 = __builtin_elementwise_fma(qv2[0][i2 + 1], kB, a0);
                a1 = __builtin_elementwise_fma(qv2[1][i2], kA, a1);
                a1 = __builtin_elementwise_fma(qv2[1][i2 + 1], kB, a1);
                a2 = __builtin_elementwise_fma(qv2[2][i2], kA, a2);
                a2 = __builtin_elementwise_fma(qv2[2][i2 + 1], kB, a2);
                a3 = __builtin_elementwise_fma(qv2[3][i2], kA, a3);
                a3 = __builtin_elementwise_fma(qv2[3][i2 + 1], kB, a3);
            }
            float p0 = a0.x + a0.y, p1 = a1.x + a1.y, p2 = a2.x + a2.y, p3 = a3.x + a3.y;
            // 4x4 transpose-reduce across the quad: lane h ends with query h's full dot
            bool b0 = (h & 1), b1 = (h & 2) != 0;
            float u0 = b0 ? p1 : p0;
            float t0 = b0 ? p0 : p1;
            u0 += dpp_xor1(t0);
            float u2 = b0 ? p3 : p2;
            float t2 = b0 ? p2 : p3;
            u2 += dpp_xor1(t2);
            float dot = b1 ? u2 : u0;
            float t3 = b1 ? u0 : u2;
            dot += dpp_xor2(t3);
            float skr = __int_as_float(kv.y) * 0.125f;       // rn_k * 0.125
            float sc = dot * skr;
            sc = (own_bk == (kv.x & 0xFFFF0000)) ? sc : -1.0e9f;  // cross-bucket mask
            if (own_w0 == kv.x) sc = -1.0e5f;          // self mask (overrides, as in ref)
            float p = __expf(sc - m_own);              // static max: no rescaling ever
            ps[j & 3] += p;
            if (loadv) {
                v2f P0 = (v2f){quad_bcast0(p), quad_bcast0(p)};
                v2f P1 = (v2f){quad_bcast1(p), quad_bcast1(p)};
                v2f P2 = (v2f){quad_bcast2(p), quad_bcast2(p)};
                v2f P3 = (v2f){quad_bcast3(p), quad_bcast3(p)};
                const float* vpj = &vt[w][j * 80 + h * 20];
                float4 vv0 = *(const float4*)(vpj + 0);
                float4 vv1 = *(const float4*)(vpj + 4);
                float4 vv2 = *(const float4*)(vpj + 8);
                float4 vv3 = *(const float4*)(vpj + 12);
                v2f vAa = (v2f){vv0.x, vv0.y}, vAb = (v2f){vv0.z, vv0.w};
                v2f vAc = (v2f){vv1.x, vv1.y}, vAd = (v2f){vv1.z, vv1.w};
                v2f vAe = (v2f){vv2.x, vv2.y}, vAf = (v2f){vv2.z, vv2.w};
                v2f vAg = (v2f){vv3.x, vv3.y}, vAh = (v2f){vv3.z, vv3.w};
                acc2[0][0] = __builtin_elementwise_fma(P0, vAa, acc2[0][0]);
                acc2[0][1] = __builtin_elementwise_fma(P0, vAb, acc2[0][1]);
                acc2[0][2] = __builtin_elementwise_fma(P0, vAc, acc2[0][2]);
                acc2[0][3] = __builtin_elementwise_fma(P0, vAd, acc2[0][3]);
                acc2[0][4] = __builtin_elementwise_fma(P0, vAe, acc2[0][4]);
                acc2[0][5] = __builtin_elementwise_fma(P0, vAf, acc2[0][5]);
                acc2[0][6] = __builtin_elementwise_fma(P0, vAg, acc2[0][6]);
                acc2[0][7] = __builtin_elementwise_fma(P0, vAh, acc2[0][7]);
                acc2[1][0] = __builtin_elementwise_fma(P1, vAa, acc2[1][0]);
                acc2[1][1] = __builtin_elementwise_fma(P1, vAb, acc2[1][1]);
                acc2[1][2] = __builtin_elementwise_fma(P1, vAc, acc2[1][2]);
                acc2[1][3] = __builtin_elementwise_fma(P1, vAd, acc2[1][3]);
                acc2[1][4] = __builtin_elementwise_fma(P1, vAe, acc2[1][4]);
                acc2[1][5] = __builtin_elementwise_fma(P1, vAf, acc2[1][5]);
                acc2[1][6] = __builtin_elementwise_fma(P1, vAg, acc2[1][6]);
                acc2[1][7] = __builtin_elementwise_fma(P1, vAh, acc2[1][7]);
                acc2[2][0] = __builtin_elementwise_fma(P2, vAa, acc2[2][0]);
                acc2[2][1] = __builtin_elementwise_fma(P2, vAb, acc2[2][1]);
                acc2[2][2] = __builtin_elementwise_fma(P2, vAc, acc2[2][2]);
                acc2[2][3] = __builtin_elementwise_fma(P2, vAd, acc2[2][3]);
                acc2[2][4] = __builtin_elementwise_fma(P2, vAe, acc2[2][4]);
                acc2[2][5] = __builtin_elementwise_fma(P2, vAf, acc2[2][5]);
                acc2[2][6] = __builtin_elementwise_fma(P2, vAg, acc2[2][6]);
                acc2[2][7] = __builtin_elementwise_fma(P2, vAh, acc2[2][7]);
                acc2[3][0] = __builtin_elementwise_fma(P3, vAa, acc2[3][0]);
                acc2[3][1] = __builtin_elementwise_fma(P3, vAb, acc2[3][1]);
                acc2[3][2] = __builtin_elementwise_fma(P3, vAc, acc2[3][2]);
                acc2[3][3] = __builtin_elementwise_fma(P3, vAd, acc2[3][3]);
                acc2[3][4] = __builtin_elementwise_fma(P3, vAe, acc2[3][4]);
                acc2[3][5] = __builtin_elementwise_fma(P3, vAf, acc2[3][5]);
                acc2[3][6] = __builtin_elementwise_fma(P3, vAg, acc2[3][6]);
                acc2[3][7] = __builtin_elementwise_fma(P3, vAh, acc2[3][7]);
            }
        }
    }
    float sum = (ps[0] + ps[1]) + (ps[2] + ps[3]);
    float lse_own, inv_own;
    if (sum > 0.0f) { lse_own = m_own + logf(sum); inv_own = 1.0f / sum; }
    else            { lse_own = -3.0e38f;          inv_own = 0.0f; }   // fully-masked row
    if (omode != 3) lse[sbase + ownpos] = lse_own;
    if (omode == 0 || omode == 1) {
        float ivs[4];
        ivs[0] = quad_bcast0(inv_own); ivs[1] = quad_bcast1(inv_own);
        ivs[2] = quad_bcast2(inv_own); ivs[3] = quad_bcast3(inv_own);
        float* cbase = contrib + ((omode == 0) ? (size_t)(b * R_ + r) * L_ : (size_t)b * L_) * D_;
        #pragma unroll
        for (int qq = 0; qq < 4; ++qq) {
            float* cp = cbase + (size_t)(posq + qq) * D_ + h * 16;
            #pragma unroll
            for (int i = 0; i < 16; i += 4) {
                int i2 = i >> 1;
                float4 o;
                o.x = acc2[qq][i2].x * ivs[qq];     o.y = acc2[qq][i2].y * ivs[qq];
                o.z = acc2[qq][i2 + 1].x * ivs[qq]; o.w = acc2[qq][i2 + 1].y * ivs[qq];
                *(float4*)(cp + i) = o;
            }
        }
    } else if (omode == 3) {
        int brr = b * R_ + r;
        float gmv = gm[brr], gsv = gs[brr];
        float ls4[4], iv4[4];
        ls4[0] = quad_bcast0(lse_own); ls4[1] = quad_bcast1(lse_own);
        ls4[2] = quad_bcast2(lse_own); ls4[3] = quad_bcast3(lse_own);
        iv4[0] = quad_bcast0(inv_own); iv4[1] = quad_bcast1(inv_own);
        iv4[2] = quad_bcast2(inv_own); iv4[3] = quad_bcast3(inv_own);
        #pragma unroll
        for (int qq = 0; qq < 4; ++qq) {
            float wq = __expf(ls4[qq] - gmv) * gsv * iv4[qq];
            float* op = out + ((size_t)b * L_ + mls[qq]) * D_ + h * 16;
            #pragma unroll
            for (int i = 0; i < 8; ++i) {
                unsafeAtomicAdd(op + 2 * i,     wq * acc2[qq][i].x);
                unsafeAtomicAdd(op + 2 * i + 1, wq * acc2[qq][i].y);
            }
        }
    }
}

// ---------------- K5: softmax-over-L normalizers (max + fp64 sum) per (b,r)
__global__ __launch_bounds__(256) void k_wred(const float* __restrict__ lse, float* __restrict__ gm,
                                              float* __restrict__ gs, int r_w) {
    __shared__ float  sm[4];
    __shared__ double sd[4];
    int br = (r_w < 0) ? (int)blockIdx.x : ((int)blockIdx.x * R_ + r_w);
    const float* x = lse + (size_t)br * L_;
    int t = threadIdx.x;
    float mx = -3.0e38f;
    for (int i = t; i < L_; i += 256) mx = fmaxf(mx, x[i]);
    #pragma unroll
    for (int o = 32; o; o >>= 1) mx = fmaxf(mx, __shfl_down(mx, o));
    if ((t & 63) == 0) sm[t >> 6] = mx;
    __syncthreads();
    mx = fmaxf(fmaxf(sm[0], sm[1]), fmaxf(sm[2], sm[3]));
    double s = 0.0;
    for (int i = t; i < L_; i += 256) s += exp((double)x[i] - (double)mx);
    #pragma unroll
    for (int o = 32; o; o >>= 1) s += __shfl_down(s, o);
    if ((t & 63) == 0) sd[t >> 6] = s;
    __syncthreads();
    if (t == 0) { gm[br] = mx; gs[br] = (float)(1.0 / (sd[0] + sd[1] + sd[2] + sd[3])); }
}

// ---------------- K6a: gather all 4 rounds from full contrib, apply w, write out
__global__ __launch_bounds__(256) void k_comb_full(const float* __restrict__ contrib,
                                                   const int* __restrict__ iv,
                                                   const float* __restrict__ lse,
                                                   const float* __restrict__ gm,
                                                   const float* __restrict__ gs,
                                                   float* __restrict__ out) {
    int gid = blockIdx.x * 256 + threadIdx.x;
    int row = gid >> 2;              // b*L + l
    int ch  = (gid & 3) * 16;
    int b = row >> 13, l = row & (L_ - 1);
    float s[16];
    #pragma unroll
    for (int i = 0; i < 16; ++i) s[i] = 0.0f;
    #pragma unroll
    for (int r = 0; r < R_; ++r) {
        int brr = b * R_ + r;
        int pos = iv[(size_t)brr * L_ + l];
        float w = expf(lse[(size_t)brr * L_ + pos] - gm[brr]) * gs[brr];
        const float* cp = contrib + ((size_t)brr * L_ + pos) * D_ + ch;
        #pragma unroll
        for (int i = 0; i < 16; i += 4) {
            float4 f = *(const float4*)(cp + i);
            s[i]   = fmaf(w, f.x, s[i]);   s[i+1] = fmaf(w, f.y, s[i+1]);
            s[i+2] = fmaf(w, f.z, s[i+2]); s[i+3] = fmaf(w, f.w, s[i+3]);
        }
    }
    float* op = out + (size_t)row * D_ + ch;
    #pragma unroll
    for (int i = 0; i < 16; i += 4) {
        float4 o; o.x = s[i]; o.y = s[i+1]; o.z = s[i+2]; o.w = s[i+3];
        *(float4*)(op + i) = o;
    }
}

// ---------------- K6b: gather one round's slice, apply w, accumulate into out
__global__ __launch_bounds__(256) void k_comb_add(const float* __restrict__ contrib,
                                                  const int* __restrict__ iv,
                                                  const float* __restrict__ lse,
                                                  const float* __restrict__ gm,
                                                  const float* __restrict__ gs,
                                                  float* __restrict__ out, int r) {
    int gid = blockIdx.x * 256 + threadIdx.x;
    int row = gid >> 2;              // b*L + l
    int ch  = (gid & 3) * 16;
    int b = row >> 13, l = row & (L_ - 1);
    int brr = b * R_ + r;
    int pos = iv[(size_t)brr * L_ + l];
    float w = expf(lse[(size_t)brr * L_ + pos] - gm[brr]) * gs[brr];
    const float* cp = contrib + ((size_t)b * L_ + pos) * D_ + ch;
    float* op = out + (size_t)row * D_ + ch;
    #pragma unroll
    for (int i = 0; i < 16; i += 4) {
        float4 f = *(const float4*)(cp + i);
        float4 o = *(const float4*)(op + i);
        o.x = fmaf(w, f.x, o.x); o.y = fmaf(w, f.y, o.y);
        o.z = fmaf(w, f.z, o.z); o.w = fmaf(w, f.w, o.w);
        *(float4*)(op + i) = o;
    }
}

// ---------------- workspace layout (bytes)
// rec (int2, 4 MB) OVERLAYS rmn (fp64, 2 MB): rmn is dead after k_hash; rec is
// written by k_sort which runs after k_hash (stream-ordered).
#define OFF_RMN     0u           // double, 2 MB (k_rmnorm -> k_hash)
#define OFF_REC     0u           // int2,   4 MB (k_sort   -> k_flash), overlays RMN
#define OFF_RN      4194304u     // float,  512 KB
#define OFF_H       4718592u     // int,    2 MB
#define OFF_LSE     6815744u     // float,  2 MB
#define OFF_GM      8912896u
#define OFF_GS      8913152u
#define OFF_INV     8913408u     // int,    2 MB
#define OFF_CONTRIB 11010560u
#define CONTRIB_FULL_BYTES  134217728ull   // B*R*L*D*4 = 128 MiB
#define CONTRIB_SLICE_BYTES 33554432ull    // B*L*D*4   =  32 MiB

extern "C" void kernel_launch(void* const* d_in, const int* in_sizes, int n_in,
                              void* d_out, int out_size, void* d_ws, size_t ws_size,
                              hipStream_t stream) {
    const float* q  = (const float*)d_in[0];
    const float* v  = (const float*)d_in[1];
    const float* rm = (const float*)d_in[2];
    float* out = (float*)d_out;
    char* ws = (char*)d_ws;
    double* rmn = (double*)(ws + OFF_RMN);
    int2*   rec = (int2*)(ws + OFF_REC);
    float*  rn  = (float*)(ws + OFF_RN);
    int*    h   = (int*)(ws + OFF_H);
    float*  lse = (float*)(ws + OFF_LSE);
    float*  gm  = (float*)(ws + OFF_GM);
    float*  gs  = (float*)(ws + OFF_GS);
    int*    iv  = (int*)(ws + OFF_INV);
    float*  contrib = (float*)(ws + OFF_CONTRIB);

    int tierA = (ws_size >= (size_t)OFF_CONTRIB + CONTRIB_FULL_BYTES) ? 1 : 0;
    int tierB = (!tierA && ws_size >= (size_t)OFF_CONTRIB + CONTRIB_SLICE_BYTES) ? 1 : 0;

    hipLaunchKernelGGL(k_rmnorm, dim3(B_ * R_), dim3(64), 0, stream, rm, rmn);
    hipLaunchKernelGGL(k_hash, dim3(L_ / 256, R_, B_), dim3(256), 0, stream, q, rmn, rn, h);
    hipLaunchKernelGGL(k_sort, dim3(B_ * R_), dim3(256), 0, stream, h, rn, iv, rec);

    if (tierA) {
        hipLaunchKernelGGL(k_flash, dim3(NB_ / 2, R_, B_), dim3(128), 0, stream, q, v, rec,
                           lse, gm, gs, out, contrib, -1, 0);
        hipLaunchKernelGGL(k_wred, dim3(B_ * R_), dim3(256), 0, stream, lse, gm, gs, -1);
        hipLaunchKernelGGL(k_comb_full, dim3(B_ * L_ * 4 / 256), dim3(256), 0, stream,
                           contrib, iv, lse, gm, gs, out);
    } else if (tierB) {
        hipMemsetAsync(d_out, 0, (size_t)B_ * L_ * D_ * sizeof(float), stream);
        for (int r = 0; r < R_; ++r) {
            hipLaunchKernelGGL(k_flash, dim3(NB_ / 2, 1, B_), dim3(128), 0, stream, q, v, rec,
                               lse, gm, gs, out, contrib, r, 1);
            hipLaunchKernelGGL(k_wred, dim3(B_), dim3(256), 0, stream, lse, gm, gs, r);
            hipLaunchKernelGGL(k_comb_add, dim3(B_ * L_ * 4 / 256), dim3(256), 0, stream,
                               contrib, iv, lse, gm, gs, out, r);
        }
    } else {
        // tier C: two flash passes (lse-only, then atomic w-weighted accumulate)
        hipMemsetAsync(d_out, 0, (size_t)B_ * L_ * D_ * sizeof(float), stream);
        hipLaunchKernelGGL(k_flash, dim3(NB_ / 2, R_, B_), dim3(128), 0, stream, q, v, rec,
                           lse, gm, gs, out, contrib, -1, 2);
        hipLaunchKernelGGL(k_wred, dim3(B_ * R_), dim3(256), 0, stream, lse, gm, gs, -1);
        hipLaunchKernelGGL(k_flash, dim3(NB_ / 2, R_, B_), dim3(128), 0, stream, q, v, rec,
                           lse, gm, gs, out, contrib, -1, 3);
    }
}